// Round 6
// baseline (165.071 us; speedup 1.0000x reference)
//
#include <hip/hip_runtime.h>
#include <hip/hip_bf16.h>

// GAT: N=4096 nodes, IN_F=256, H=4 heads, D=64.
// K0 gat_pack : adj (64 MB int) -> adjb bitmask (2 MB), coalesced streaming.
// K1 gat_prep : h = x@W (fp32), siT = <h,a1>*log2e, vv2T = {exp2(sj), exp2(0.2*sj)},
//               hT bf16 [H][D][N], per-block sj-max partials.
// K2 gat_attn : masked softmax + PV via mfma_16x16x32_bf16.
//               m_i = leaky(si + max_j sj) upper bound -> pure-sum softmax.
//               64-row tiles x 4 heads x 2 j-splits. Per-128-j window:
//               global_load_lds stages hT in MFMA-fragment lane order + vv2;
//               masks = direct global dwords (L2-resident bitmask), prefetched.
//               Double-buffered, 1 barrier/window. j-split partials -> ws.
// K3 gat_reduce: out = (p0+p1)/(l0+l1).

typedef __bf16 bf16x8 __attribute__((ext_vector_type(8)));
typedef float floatx4 __attribute__((ext_vector_type(4)));

#define LOG2E 1.4426950408889634f
#define NN 4096

__device__ __forceinline__ void gl16(const void* g, void* l) {
  __builtin_amdgcn_global_load_lds(
      (const __attribute__((address_space(1))) unsigned int*)g,
      (__attribute__((address_space(3))) unsigned int*)l, 16, 0, 0);
}

// ---------------- Kernel 0: adj -> bitmask ----------------
__global__ __launch_bounds__(256) void gat_pack(const int* __restrict__ adj,
                                                unsigned char* __restrict__ adjb) {
  int T = blockIdx.x * 256 + threadIdx.x;
  const int stride = 2048 * 256;
#pragma unroll
  for (int it = 0; it < 4; ++it, T += stride) {
    const int* p = adj + (size_t)T * 8;
    int4 a = *(const int4*)p;
    int4 b = *(const int4*)(p + 4);
    unsigned int m = 0;
    m |= (a.x != 0) ? 1u : 0u;
    m |= (a.y != 0) ? 2u : 0u;
    m |= (a.z != 0) ? 4u : 0u;
    m |= (a.w != 0) ? 8u : 0u;
    m |= (b.x != 0) ? 16u : 0u;
    m |= (b.y != 0) ? 32u : 0u;
    m |= (b.z != 0) ? 64u : 0u;
    m |= (b.w != 0) ? 128u : 0u;
    adjb[T] = (unsigned char)m;
  }
}

// ---------------- Kernel 1: h = x@W + per-row scalars + hT(bf16) ----------------
__global__ __launch_bounds__(256) void gat_prep(
    const float* __restrict__ x, const float* __restrict__ W,
    const float* __restrict__ a1, const float* __restrict__ a2,
    __bf16* __restrict__ hT, float* __restrict__ siT, float2* __restrict__ vv2T,
    float* __restrict__ sjm) {
  __shared__ float hl[32 * 68];
  __shared__ float sjb[32];
  const int t = threadIdx.x;
  const int it = blockIdx.x, hh = blockIdx.y;
  const int i0 = it * 32, c0 = hh * 64;
  const int tr = t >> 4, tc = t & 15;

  float acc[2][4] = {{0.f,0.f,0.f,0.f},{0.f,0.f,0.f,0.f}};
  const float* xr = x + (size_t)(i0 + tr * 2) * 256;
  const float* wp = W + c0 + tc * 4;
  for (int k = 0; k < 256; k += 4) {
    float4 xv0 = *(const float4*)(xr + k);
    float4 xv1 = *(const float4*)(xr + 256 + k);
    float xs[2][4] = {{xv0.x, xv0.y, xv0.z, xv0.w},
                      {xv1.x, xv1.y, xv1.z, xv1.w}};
#pragma unroll
    for (int kk = 0; kk < 4; ++kk) {
      float4 wv = *(const float4*)(wp + (size_t)(k + kk) * 256);
#pragma unroll
      for (int i = 0; i < 2; ++i) {
        acc[i][0] = fmaf(xs[i][kk], wv.x, acc[i][0]);
        acc[i][1] = fmaf(xs[i][kk], wv.y, acc[i][1]);
        acc[i][2] = fmaf(xs[i][kk], wv.z, acc[i][2]);
        acc[i][3] = fmaf(xs[i][kk], wv.w, acc[i][3]);
      }
    }
  }

  float4 a1v = *(const float4*)(a1 + tc * 4);
  float4 a2v = *(const float4*)(a2 + tc * 4);
#pragma unroll
  for (int i = 0; i < 2; ++i) {
    float s1 = acc[i][0]*a1v.x + acc[i][1]*a1v.y + acc[i][2]*a1v.z + acc[i][3]*a1v.w;
    float s2 = acc[i][0]*a2v.x + acc[i][1]*a2v.y + acc[i][2]*a2v.z + acc[i][3]*a2v.w;
#pragma unroll
    for (int off = 1; off < 16; off <<= 1) {
      s1 += __shfl_xor(s1, off);
      s2 += __shfl_xor(s2, off);
    }
    if (tc == 0) {
      int r = tr * 2 + i;
      siT[hh * NN + i0 + r] = s1 * LOG2E;
      float sjs = s2 * LOG2E;
      vv2T[hh * NN + i0 + r] =
          make_float2(__builtin_amdgcn_exp2f(sjs), __builtin_amdgcn_exp2f(0.2f * sjs));
      sjb[r] = sjs;
    }
    *(float4*)&hl[(tr * 2 + i) * 68 + tc * 4] =
        make_float4(acc[i][0], acc[i][1], acc[i][2], acc[i][3]);
  }
  __syncthreads();

  if (t < 32) {
    float v = sjb[t];
#pragma unroll
    for (int off = 1; off < 32; off <<= 1) v = fmaxf(v, __shfl_xor(v, off));
    if (t == 0) sjm[it * 4 + hh] = v;
  }

  const int d = t & 63, g = t >> 6;
  bf16x8 h0;
#pragma unroll
  for (int ii = 0; ii < 8; ++ii) h0[ii] = (__bf16)hl[(g * 8 + ii) * 68 + d];
  *(bf16x8*)(hT + (size_t)(hh * 64 + d) * NN + i0 + g * 8) = h0;
}

// ---------------- Kernel 2: masked softmax + PV (MFMA) ----------------
// grid (64 i-tiles of 64 rows, 4 heads, 2 j-splits), 256 threads = 4 waves;
// wave w owns j-offset w*32 within each 128-j window; 16 windows per block.
__global__ __launch_bounds__(256, 2) void gat_attn(
    const __bf16* __restrict__ hT, const float* __restrict__ siT,
    const float2* __restrict__ vv2T, const float* __restrict__ sjm,
    const unsigned int* __restrict__ adjw,
    float* __restrict__ pacc, float* __restrict__ pl) {
  // LDS: [0,16384) hT buf0 | [16384,32768) hT buf1 | [32768,33792) vv2 buf0
  //      [33792,34816) vv2 buf1
  // epilogue alias: accs f32[2][64][68] @0 (34816 B), lsum f32[2][64] @34816
  __shared__ __align__(16) char lds[35328];
  const int t = threadIdx.x;
  const int w = t >> 6, lane = t & 63, quad = lane >> 4, l16 = lane & 15;
  const int i0 = blockIdx.x * 64, hh = blockIdx.y, s = blockIdx.z;
  const int jbeg = s * 2048;

  const __bf16* hTw = hT + (size_t)hh * 64 * NN + jbeg + w * 32 + quad * 8;
  const float2* vw = vv2T + hh * NN + jbeg;

  // per-lane hT fragment gather offsets (elements) for the 4 d-subtiles
  int hoff[4];
#pragma unroll
  for (int nt = 0; nt < 4; ++nt) hoff[nt] = (nt * 16 + l16) * NN;

  // mask pointers: row (i0 + mt*16 + l16), dword (jbeg/32 + win*4 + w)
  const unsigned int* mp[4];
#pragma unroll
  for (int mt = 0; mt < 4; ++mt)
    mp[mt] = adjw + (size_t)(i0 + mt * 16 + l16) * 128 + (jbeg >> 5) + w;

  // ---- stage window 0 into buf0, load window-0 masks ----
#pragma unroll
  for (int nt = 0; nt < 4; ++nt)
    gl16(hTw + hoff[nt], lds + ((w * 4 + nt) << 10) + (lane << 4));
  if (w == 0) gl16(vw + lane * 2, lds + 32768 + (lane << 4));
  unsigned int mc[4], mn[4];
#pragma unroll
  for (int mt = 0; mt < 4; ++mt) mc[mt] = mp[mt][0];

  // ---- per-row constants (overlaps staging) ----
  float vv = fmaxf(sjm[lane * 4 + hh], sjm[(lane + 64) * 4 + hh]);
#pragma unroll
  for (int off = 1; off < 64; off <<= 1) vv = fmaxf(vv, __shfl_xor(vv, off));
  float u[4], u2[4];
#pragma unroll
  for (int mt = 0; mt < 4; ++mt) {
    float sis = siT[hh * NN + i0 + mt * 16 + l16];
    float tt = sis + vv;
    float m = fmaxf(tt, 0.2f * tt);   // leaky monotone -> valid row-max upper bound
    u[mt] = __builtin_amdgcn_exp2f(sis - m);
    u2[mt] = __builtin_amdgcn_exp2f(0.2f * sis - m);
  }

  bf16x8 ones;
#pragma unroll
  for (int ii = 0; ii < 8; ++ii) ones[ii] = (__bf16)1.0f;

  floatx4 zv = {0.f, 0.f, 0.f, 0.f};
  floatx4 acc[4][4], lacc[4];
#pragma unroll
  for (int mt = 0; mt < 4; ++mt) {
    lacc[mt] = zv;
#pragma unroll
    for (int nt = 0; nt < 4; ++nt) acc[mt][nt] = zv;
  }

  __syncthreads();   // window 0 staged

  for (int win = 0; win < 16; ++win) {
    const int p = win & 1;
    const char* hb = lds + (p << 14);
    const char* vb = lds + 32768 + (p << 10);

    if (win + 1 < 16) {
      // prefetch next-window masks FIRST (oldest in vmcnt FIFO)
#pragma unroll
      for (int mt = 0; mt < 4; ++mt) mn[mt] = mp[mt][(win + 1) * 4];
      // stage next window into the other buffer
      const int jn = (win + 1) << 7;
      char* hbn = lds + ((p ^ 1) << 14);
#pragma unroll
      for (int nt = 0; nt < 4; ++nt)
        gl16(hTw + hoff[nt] + jn, hbn + ((w * 4 + nt) << 10) + (lane << 4));
      if (w == 0)
        gl16(vw + jn + lane * 2, lds + 32768 + ((p ^ 1) << 10) + (lane << 4));
    }

    // hT B-fragments: contiguous lane-order ds_read_b128
    bf16x8 bfr[4];
#pragma unroll
    for (int nt = 0; nt < 4; ++nt)
      bfr[nt] = *(const bf16x8*)(hb + ((w * 4 + nt) << 10) + (lane << 4));
    // vv2: broadcast reads {v,v2,v,v2} per j-pair
    float4 q[4];
#pragma unroll
    for (int c = 0; c < 4; ++c)
      q[c] = *(const float4*)(vb + (w << 8) + (quad << 6) + (c << 4));

#pragma unroll
    for (int mt = 0; mt < 4; ++mt) {
      unsigned int m8 = mc[mt] >> (quad * 8);
      bf16x8 af;
#pragma unroll
      for (int c = 0; c < 4; ++c) {
        float p0 = fmaxf(u[mt] * q[c].x, u2[mt] * q[c].y);
        float p1 = fmaxf(u[mt] * q[c].z, u2[mt] * q[c].w);
        // sign-extended 1-bit BFE -> bitwise AND (2 VALU, no cmp/cndmask)
        int b0 = ((int)(m8 << (31 - 2 * c))) >> 31;
        int b1 = ((int)(m8 << (30 - 2 * c))) >> 31;
        af[2 * c]     = (__bf16)__uint_as_float(__float_as_uint(p0) & (unsigned)b0);
        af[2 * c + 1] = (__bf16)__uint_as_float(__float_as_uint(p1) & (unsigned)b1);
      }
#pragma unroll
      for (int nt = 0; nt < 4; ++nt)
        acc[mt][nt] = __builtin_amdgcn_mfma_f32_16x16x32_bf16(af, bfr[nt],
                                                              acc[mt][nt], 0, 0, 0);
      lacc[mt] = __builtin_amdgcn_mfma_f32_16x16x32_bf16(af, ones, lacc[mt], 0, 0, 0);
    }
#pragma unroll
    for (int mt = 0; mt < 4; ++mt) mc[mt] = mn[mt];
    __syncthreads();
  }

  // epilogue: combine the 4 j-split waves in LDS (aliases dead staging bufs)
  float* accs = (float*)lds;             // [2][64][68]
  float* lsum = (float*)(lds + 34816);   // [2][64]
  // C layout: row = mt*16 + quad*4 + reg, col = nt*16 + l16
  if (w < 2) {
#pragma unroll
    for (int mt = 0; mt < 4; ++mt)
#pragma unroll
      for (int reg = 0; reg < 4; ++reg) {
        int row = mt * 16 + quad * 4 + reg;
        float* ap = accs + (w * 64 + row) * 68;
#pragma unroll
        for (int nt = 0; nt < 4; ++nt)
          ap[nt * 16 + l16] = acc[mt][nt][reg];
        if (l16 == 0) lsum[w * 64 + row] = lacc[mt][reg];
      }
  }
  __syncthreads();
  if (w >= 2) {
    const int b = w - 2;
#pragma unroll
    for (int mt = 0; mt < 4; ++mt)
#pragma unroll
      for (int reg = 0; reg < 4; ++reg) {
        int row = mt * 16 + quad * 4 + reg;
        float* ap = accs + (b * 64 + row) * 68;
#pragma unroll
        for (int nt = 0; nt < 4; ++nt)
          ap[nt * 16 + l16] += acc[mt][nt][reg];
        if (l16 == 0) lsum[b * 64 + row] += lacc[mt][reg];
      }
  }
  __syncthreads();

  // write partials: r = t>>2 (64 rows), cbase = (t&3)*16 (16 cols per thread)
  const int r = t >> 2, cb = (t & 3) * 16;
  float* op = pacc + (size_t)s * NN * 256 + (size_t)(i0 + r) * 256 + hh * 64 + cb;
#pragma unroll
  for (int c4 = 0; c4 < 4; ++c4) {
    int c = cb + c4 * 4;
    float4 o;
    o.x = accs[r * 68 + c + 0] + accs[(64 + r) * 68 + c + 0];
    o.y = accs[r * 68 + c + 1] + accs[(64 + r) * 68 + c + 1];
    o.z = accs[r * 68 + c + 2] + accs[(64 + r) * 68 + c + 2];
    o.w = accs[r * 68 + c + 3] + accs[(64 + r) * 68 + c + 3];
    *(float4*)(op + c4 * 4) = o;
  }
  if (t < 64)
    pl[(size_t)s * NN * 4 + (i0 + t) * 4 + hh] = lsum[t] + lsum[64 + t];
}

// ---------------- Kernel 3: combine j-splits + normalize ----------------
__global__ __launch_bounds__(256) void gat_reduce(
    const float* __restrict__ pacc, const float* __restrict__ pl,
    float* __restrict__ out) {
  const int e4 = blockIdx.x * 256 + threadIdx.x;
  const int e = e4 * 4;                 // e = i*256 + h*64 + d
  const int i = e >> 8;
  const int h = (e & 255) >> 6;
  float4 a0 = *(const float4*)(pacc + e);
  float4 a1 = *(const float4*)(pacc + (size_t)NN * 256 + e);
  float l = pl[i * 4 + h] + pl[(size_t)NN * 4 + i * 4 + h];
  float inv = 1.0f / l;
  *(float4*)(out + e) = make_float4((a0.x + a1.x) * inv, (a0.y + a1.y) * inv,
                                    (a0.z + a1.z) * inv, (a0.w + a1.w) * inv);
}

extern "C" void kernel_launch(void* const* d_in, const int* in_sizes, int n_in,
                              void* d_out, int out_size, void* d_ws, size_t ws_size,
                              hipStream_t stream) {
  const float* x  = (const float*)d_in[0];
  const int*   adj = (const int*)d_in[1];
  const float* W  = (const float*)d_in[2];
  const float* a1 = (const float*)d_in[3];
  const float* a2 = (const float*)d_in[4];
  float* out = (float*)d_out;
  char* ws = (char*)d_ws;

  // ws layout (bytes):
  //   hT   bf16   [4][64][4096] @ 0        (2 MiB)
  //   siT  f32    [4][4096]     @ 2097152  (64 KiB)
  //   vv2T f32x2  [4][4096]     @ 2162688  (128 KiB)
  //   sjm  f32    [128][4]      @ 2293760  (2 KiB)
  //   adjb u8     [4096][512]   @ 2295808  (2 MiB bitmask)
  //   pacc f32    [2][4096][256]@ 4392960  (8 MiB)
  //   pl   f32    [2][4096][4]  @ 12781568 (128 KiB)
  __bf16* hT   = (__bf16*)ws;
  float*  siT  = (float*)(ws + 2097152);
  float2* vv2T = (float2*)(ws + 2162688);
  float*  sjm  = (float*)(ws + 2293760);
  unsigned char* adjb = (unsigned char*)(ws + 2295808);
  float*  pacc = (float*)(ws + 4392960);
  float*  pl   = (float*)(ws + 12781568);

  gat_pack<<<2048, 256, 0, stream>>>(adj, adjb);
  gat_prep<<<dim3(128, 4), 256, 0, stream>>>(x, W, a1, a2, hT, siT, vv2T, sjm);
  gat_attn<<<dim3(64, 4, 2), 256, 0, stream>>>(hT, siT, vv2T, sjm,
                                               (const unsigned int*)adjb, pacc, pl);
  gat_reduce<<<1024, 256, 0, stream>>>(pacc, pl, out);
}

// Round 7
// 157.183 us; speedup vs baseline: 1.0502x; 1.0502x over previous
//
#include <hip/hip_runtime.h>
#include <hip/hip_bf16.h>

// GAT: N=4096 nodes, IN_F=256, H=4 heads, D=64.
// K1 gat_prep : fused. blocks [0,512): h = x@W (fp32), siT = <h,a1>*log2e,
//               vv2T = {exp2(sj), exp2(0.2*sj)}, hTf bf16 in MFMA-fragment-major
//               layout [h][j-chunk][nt][lane], per-block sj-max partials.
//               blocks [512,2560): adj (64 MB int) -> adjb bitmask (2 MB).
// K2 gat_attn : masked softmax + PV via mfma_16x16x32_bf16.
//               m_i = leaky(si + max_j sj) upper bound -> pure-sum softmax.
//               64-row tiles x 4 heads x 2 j-splits; 256-j LDS windows double-
//               buffered (32KBx2), staged with contiguous-1KB global_load_lds;
//               masks+vv2 register-prefetched (drained free by window barrier).
// K3 gat_reduce: out = (p0+p1)/(l0+l1).

typedef __bf16 bf16x8 __attribute__((ext_vector_type(8)));
typedef float floatx4 __attribute__((ext_vector_type(4)));

#define LOG2E 1.4426950408889634f
#define NN 4096

__device__ __forceinline__ void gl16(const void* g, void* l) {
  __builtin_amdgcn_global_load_lds(
      (const __attribute__((address_space(1))) unsigned int*)g,
      (__attribute__((address_space(3))) unsigned int*)l, 16, 0, 0);
}

// ---------------- Kernel 1: fused prep + pack ----------------
// blocks [0,512): prep (it = b&127 -> 32-row tile, hh = b>>7)
// blocks [512,2560): pack
__global__ __launch_bounds__(256) void gat_prep(
    const float* __restrict__ x, const float* __restrict__ W,
    const float* __restrict__ a1, const float* __restrict__ a2,
    const int* __restrict__ adj, __bf16* __restrict__ hTf,
    float* __restrict__ siT, float2* __restrict__ vv2T, float* __restrict__ sjm,
    unsigned char* __restrict__ adjb) {
  const int b = blockIdx.x;
  const int t = threadIdx.x;

  if (b >= 512) {  // ---- pack: adj -> bitmask ----
    int T = (b - 512) * 256 + t;
    const int stride = 2048 * 256;
#pragma unroll
    for (int it = 0; it < 4; ++it, T += stride) {
      const int* p = adj + (size_t)T * 8;
      int4 a = *(const int4*)p;
      int4 bb = *(const int4*)(p + 4);
      unsigned int m = 0;
      m |= (a.x != 0) ? 1u : 0u;
      m |= (a.y != 0) ? 2u : 0u;
      m |= (a.z != 0) ? 4u : 0u;
      m |= (a.w != 0) ? 8u : 0u;
      m |= (bb.x != 0) ? 16u : 0u;
      m |= (bb.y != 0) ? 32u : 0u;
      m |= (bb.z != 0) ? 64u : 0u;
      m |= (bb.w != 0) ? 128u : 0u;
      adjb[T] = (unsigned char)m;
    }
    return;
  }

  // ---- prep ----
  __shared__ float hl[32 * 68];
  __shared__ float sjb[32];
  const int it = b & 127, hh = b >> 7;
  const int i0 = it * 32, c0 = hh * 64;
  const int tr = t >> 4, tc = t & 15;

  float acc[2][4] = {{0.f,0.f,0.f,0.f},{0.f,0.f,0.f,0.f}};
  const float* xr = x + (size_t)(i0 + tr * 2) * 256;
  const float* wp = W + c0 + tc * 4;
  for (int k = 0; k < 256; k += 4) {
    float4 xv0 = *(const float4*)(xr + k);
    float4 xv1 = *(const float4*)(xr + 256 + k);
    float xs[2][4] = {{xv0.x, xv0.y, xv0.z, xv0.w},
                      {xv1.x, xv1.y, xv1.z, xv1.w}};
#pragma unroll
    for (int kk = 0; kk < 4; ++kk) {
      float4 wv = *(const float4*)(wp + (size_t)(k + kk) * 256);
#pragma unroll
      for (int i = 0; i < 2; ++i) {
        acc[i][0] = fmaf(xs[i][kk], wv.x, acc[i][0]);
        acc[i][1] = fmaf(xs[i][kk], wv.y, acc[i][1]);
        acc[i][2] = fmaf(xs[i][kk], wv.z, acc[i][2]);
        acc[i][3] = fmaf(xs[i][kk], wv.w, acc[i][3]);
      }
    }
  }

  float4 a1v = *(const float4*)(a1 + tc * 4);
  float4 a2v = *(const float4*)(a2 + tc * 4);
#pragma unroll
  for (int i = 0; i < 2; ++i) {
    float s1 = acc[i][0]*a1v.x + acc[i][1]*a1v.y + acc[i][2]*a1v.z + acc[i][3]*a1v.w;
    float s2 = acc[i][0]*a2v.x + acc[i][1]*a2v.y + acc[i][2]*a2v.z + acc[i][3]*a2v.w;
#pragma unroll
    for (int off = 1; off < 16; off <<= 1) {
      s1 += __shfl_xor(s1, off);
      s2 += __shfl_xor(s2, off);
    }
    if (tc == 0) {
      int r = tr * 2 + i;
      siT[hh * NN + i0 + r] = s1 * LOG2E;
      float sjs = s2 * LOG2E;
      vv2T[hh * NN + i0 + r] =
          make_float2(__builtin_amdgcn_exp2f(sjs), __builtin_amdgcn_exp2f(0.2f * sjs));
      sjb[r] = sjs;
    }
    *(float4*)&hl[(tr * 2 + i) * 68 + tc * 4] =
        make_float4(acc[i][0], acc[i][1], acc[i][2], acc[i][3]);
  }
  __syncthreads();

  if (t < 32) {
    float v = sjb[t];
#pragma unroll
    for (int off = 1; off < 32; off <<= 1) v = fmaxf(v, __shfl_xor(v, off));
    if (t == 0) sjm[it * 4 + hh] = v;
  }

  // fragment-major hTf: chunk it (j = i0 + quad*8 + jj), subtile nt = wave id,
  // lane holds B-frag 16B: hT[d = nt*16+l16][j = i0 + quad*8 .. +7]
  const int nt = t >> 6, lane = t & 63, quad = lane >> 4, l16 = lane & 15;
  bf16x8 h0;
#pragma unroll
  for (int jj = 0; jj < 8; ++jj)
    h0[jj] = (__bf16)hl[(quad * 8 + jj) * 68 + nt * 16 + l16];
  *(bf16x8*)((char*)hTf + ((((size_t)hh * 128 + it) * 4 + nt) << 10) + (lane << 4)) = h0;
}

// ---------------- Kernel 2: masked softmax + PV (MFMA) ----------------
// grid (64 i-tiles of 64 rows, 4 heads, 2 j-splits), 256 threads = 4 waves;
// wave w owns j-offset w*64 within each 256-j window; 8 windows per block.
__global__ __launch_bounds__(256, 2) void gat_attn(
    const __bf16* __restrict__ hTf, const float* __restrict__ siT,
    const float2* __restrict__ vv2T, const float* __restrict__ sjm,
    const unsigned int* __restrict__ adjw,
    float* __restrict__ pacc, float* __restrict__ pl) {
  // LDS: hT buf0 [0,32768) | hT buf1 [32768,65536)
  // epilogue alias: accs f32[2][64][68] @0 (34816 B), lsum f32[2][64] @34816
  __shared__ __align__(16) char lds[65536];
  const int t = threadIdx.x;
  const int w = t >> 6, lane = t & 63, quad = lane >> 4, l16 = lane & 15;
  const int i0 = blockIdx.x * 64, hh = blockIdx.y, s = blockIdx.z;
  const int jbeg = s * 2048;

  // staging source: this wave's first chunk (chunk = 32 j = 4 KB), + lane*16
  const char* hsrc = (const char*)hTf +
      (((size_t)hh * 128 + (jbeg >> 5) + w * 2) << 12) + (lane << 4);
  const float2* vw = vv2T + (size_t)hh * NN + jbeg + w * 64;

  const unsigned int* mp[4];
#pragma unroll
  for (int mt = 0; mt < 4; ++mt)
    mp[mt] = adjw + (size_t)(i0 + mt * 16 + l16) * 128 + (jbeg >> 5) + w * 2;

  // ---- prefetch window 0: masks + vv2 (regs), hT (LDS buf0) ----
  uint2 mc[4], mn[4];
  float4 qc[2][4], qn[2][4];
#pragma unroll
  for (int mt = 0; mt < 4; ++mt) mc[mt] = *(const uint2*)mp[mt];
#pragma unroll
  for (int k = 0; k < 2; ++k) {
    const float4* qp = (const float4*)(vw + k * 32 + quad * 8);
#pragma unroll
    for (int c = 0; c < 4; ++c) qc[k][c] = qp[c];
  }
#pragma unroll
  for (int k = 0; k < 2; ++k)
#pragma unroll
    for (int nt = 0; nt < 4; ++nt)
      gl16(hsrc + ((k * 4 + nt) << 10),
           lds + (((w * 8 + k * 4 + nt) << 10) + (lane << 4)));

  // ---- per-row constants (overlaps staging) ----
  float vv = fmaxf(sjm[lane * 4 + hh], sjm[(lane + 64) * 4 + hh]);
#pragma unroll
  for (int off = 1; off < 64; off <<= 1) vv = fmaxf(vv, __shfl_xor(vv, off));
  float u[4], u2[4];
#pragma unroll
  for (int mt = 0; mt < 4; ++mt) {
    float sis = siT[hh * NN + i0 + mt * 16 + l16];
    float tt = sis + vv;
    float m = fmaxf(tt, 0.2f * tt);   // leaky monotone -> valid row-max upper bound
    u[mt] = __builtin_amdgcn_exp2f(sis - m);
    u2[mt] = __builtin_amdgcn_exp2f(0.2f * sis - m);
  }

  bf16x8 ones;
#pragma unroll
  for (int ii = 0; ii < 8; ++ii) ones[ii] = (__bf16)1.0f;

  floatx4 zv = {0.f, 0.f, 0.f, 0.f};
  floatx4 acc[4][4], lacc[4];
#pragma unroll
  for (int mt = 0; mt < 4; ++mt) {
    lacc[mt] = zv;
#pragma unroll
    for (int nt = 0; nt < 4; ++nt) acc[mt][nt] = zv;
  }

  __syncthreads();   // window 0 staged

  for (int win = 0; win < 8; ++win) {
    const int p = win & 1;
    const char* hb = lds + p * 32768;

    if (win + 1 < 8) {  // prefetch next window: regs first, then LDS staging
#pragma unroll
      for (int mt = 0; mt < 4; ++mt)
        mn[mt] = *(const uint2*)(mp[mt] + (win + 1) * 8);
#pragma unroll
      for (int k = 0; k < 2; ++k) {
        const float4* qp = (const float4*)(vw + (win + 1) * 256 + k * 32 + quad * 8);
#pragma unroll
        for (int c = 0; c < 4; ++c) qn[k][c] = qp[c];
      }
      char* hbn = lds + (p ^ 1) * 32768;
      const char* hs = hsrc + (win + 1) * 32768;
#pragma unroll
      for (int k = 0; k < 2; ++k)
#pragma unroll
        for (int nt = 0; nt < 4; ++nt)
          gl16(hs + ((k * 4 + nt) << 10),
               hbn + (((w * 8 + k * 4 + nt) << 10) + (lane << 4)));
    }

#pragma unroll
    for (int k = 0; k < 2; ++k) {
      bf16x8 bfr[4];
#pragma unroll
      for (int nt = 0; nt < 4; ++nt)
        bfr[nt] = *(const bf16x8*)(hb + ((w * 8 + k * 4 + nt) << 10) + (lane << 4));
#pragma unroll
      for (int mt = 0; mt < 4; ++mt) {
        unsigned int m8 = (k ? mc[mt].y : mc[mt].x) >> (quad * 8);
        bf16x8 af;
#pragma unroll
        for (int c = 0; c < 4; ++c) {
          float p0 = fmaxf(u[mt] * qc[k][c].x, u2[mt] * qc[k][c].y);
          float p1 = fmaxf(u[mt] * qc[k][c].z, u2[mt] * qc[k][c].w);
          // sign-extended 1-bit extract -> bitwise AND (2 VALU, no cmp/cndmask)
          int b0 = ((int)(m8 << (31 - 2 * c))) >> 31;
          int b1 = ((int)(m8 << (30 - 2 * c))) >> 31;
          af[2 * c]     = (__bf16)__uint_as_float(__float_as_uint(p0) & (unsigned)b0);
          af[2 * c + 1] = (__bf16)__uint_as_float(__float_as_uint(p1) & (unsigned)b1);
        }
#pragma unroll
        for (int nt = 0; nt < 4; ++nt)
          acc[mt][nt] = __builtin_amdgcn_mfma_f32_16x16x32_bf16(af, bfr[nt],
                                                                acc[mt][nt], 0, 0, 0);
        lacc[mt] = __builtin_amdgcn_mfma_f32_16x16x32_bf16(af, ones, lacc[mt], 0, 0, 0);
      }
    }
#pragma unroll
    for (int mt = 0; mt < 4; ++mt) mc[mt] = mn[mt];
#pragma unroll
    for (int k = 0; k < 2; ++k)
#pragma unroll
      for (int c = 0; c < 4; ++c) qc[k][c] = qn[k][c];
    __syncthreads();
  }

  // epilogue: combine the 4 j-split waves in LDS (aliases dead staging bufs)
  float* accs = (float*)lds;             // [2][64][68]
  float* lsum = (float*)(lds + 34816);   // [2][64]
  // C layout: row = mt*16 + quad*4 + reg, col = nt*16 + l16
  if (w < 2) {
#pragma unroll
    for (int mt = 0; mt < 4; ++mt)
#pragma unroll
      for (int reg = 0; reg < 4; ++reg) {
        int row = mt * 16 + quad * 4 + reg;
        float* ap = accs + (w * 64 + row) * 68;
#pragma unroll
        for (int nt = 0; nt < 4; ++nt)
          ap[nt * 16 + l16] = acc[mt][nt][reg];
        if (l16 == 0) lsum[w * 64 + row] = lacc[mt][reg];
      }
  }
  __syncthreads();
  if (w >= 2) {
    const int bb = w - 2;
#pragma unroll
    for (int mt = 0; mt < 4; ++mt)
#pragma unroll
      for (int reg = 0; reg < 4; ++reg) {
        int row = mt * 16 + quad * 4 + reg;
        float* ap = accs + (bb * 64 + row) * 68;
#pragma unroll
        for (int nt = 0; nt < 4; ++nt)
          ap[nt * 16 + l16] += acc[mt][nt][reg];
        if (l16 == 0) lsum[bb * 64 + row] += lacc[mt][reg];
      }
  }
  __syncthreads();

  // write partials: r = t>>2 (64 rows), cbase = (t&3)*16 (16 cols per thread)
  const int r = t >> 2, cb = (t & 3) * 16;
  float* op = pacc + (size_t)s * NN * 256 + (size_t)(i0 + r) * 256 + hh * 64 + cb;
#pragma unroll
  for (int c4 = 0; c4 < 4; ++c4) {
    int c = cb + c4 * 4;
    float4 o;
    o.x = accs[r * 68 + c + 0] + accs[(64 + r) * 68 + c + 0];
    o.y = accs[r * 68 + c + 1] + accs[(64 + r) * 68 + c + 1];
    o.z = accs[r * 68 + c + 2] + accs[(64 + r) * 68 + c + 2];
    o.w = accs[r * 68 + c + 3] + accs[(64 + r) * 68 + c + 3];
    *(float4*)(op + c4 * 4) = o;
  }
  if (t < 64)
    pl[(size_t)s * NN * 4 + (i0 + t) * 4 + hh] = lsum[t] + lsum[64 + t];
}

// ---------------- Kernel 3: combine j-splits + normalize ----------------
__global__ __launch_bounds__(256) void gat_reduce(
    const float* __restrict__ pacc, const float* __restrict__ pl,
    float* __restrict__ out) {
  const int e4 = blockIdx.x * 256 + threadIdx.x;
  const int e = e4 * 4;                 // e = i*256 + h*64 + d
  const int i = e >> 8;
  const int h = (e & 255) >> 6;
  float4 a0 = *(const float4*)(pacc + e);
  float4 a1 = *(const float4*)(pacc + (size_t)NN * 256 + e);
  float l = pl[i * 4 + h] + pl[(size_t)NN * 4 + i * 4 + h];
  float inv = 1.0f / l;
  *(float4*)(out + e) = make_float4((a0.x + a1.x) * inv, (a0.y + a1.y) * inv,
                                    (a0.z + a1.z) * inv, (a0.w + a1.w) * inv);
}

extern "C" void kernel_launch(void* const* d_in, const int* in_sizes, int n_in,
                              void* d_out, int out_size, void* d_ws, size_t ws_size,
                              hipStream_t stream) {
  const float* x  = (const float*)d_in[0];
  const int*   adj = (const int*)d_in[1];
  const float* W  = (const float*)d_in[2];
  const float* a1 = (const float*)d_in[3];
  const float* a2 = (const float*)d_in[4];
  float* out = (float*)d_out;
  char* ws = (char*)d_ws;

  // ws layout (bytes):
  //   hTf  bf16   [4][128][4][1024B] @ 0   (2 MiB, fragment-major)
  //   siT  f32    [4][4096]     @ 2097152  (64 KiB)
  //   vv2T f32x2  [4][4096]     @ 2162688  (128 KiB)
  //   sjm  f32    [128][4]      @ 2293760  (2 KiB)
  //   adjb u8     [4096][512]   @ 2295808  (2 MiB bitmask)
  //   pacc f32    [2][4096][256]@ 4392960  (8 MiB)
  //   pl   f32    [2][4096][4]  @ 12781568 (128 KiB)
  __bf16* hTf  = (__bf16*)ws;
  float*  siT  = (float*)(ws + 2097152);
  float2* vv2T = (float2*)(ws + 2162688);
  float*  sjm  = (float*)(ws + 2293760);
  unsigned char* adjb = (unsigned char*)(ws + 2295808);
  float*  pacc = (float*)(ws + 4392960);
  float*  pl   = (float*)(ws + 12781568);

  gat_prep<<<2560, 256, 0, stream>>>(x, W, a1, a2, adj, hTf, siT, vv2T, sjm, adjb);
  gat_attn<<<dim3(64, 4, 2), 256, 0, stream>>>(hTf, siT, vv2T, sjm,
                                               (const unsigned int*)adjb, pacc, pl);
  gat_reduce<<<1024, 256, 0, stream>>>(pacc, pl, out);
}